// Round 1
// baseline (1987.543 us; speedup 1.0000x reference)
//
#include <hip/hip_runtime.h>
#include <math.h>

#define BB 8
#define NN 2048
#define DD 256
#define NP 2049
#define RCH 16          // row chunks for column pass
#define CHUNK 129       // ceil(2049/16)
#define CT 9            // ceil(2049/256) column tiles
#define LOG2048 7.624618986159398f

__device__ __forceinline__ void lse_comb(float& m, float& s, float om, float os) {
    float nm = fmaxf(m, om);
    s = s * __expf(m - nm) + os * __expf(om - nm);
    m = nm;
}

// ---------------- norms: n[b][r] = sum_d d[b][r][d]^2 ----------------
__global__ __launch_bounds__(256) void norms_k(const float* __restrict__ d1,
                                               const float* __restrict__ d2,
                                               float* __restrict__ n1,
                                               float* __restrict__ n2) {
    const float* d = blockIdx.z ? d2 : d1;
    float* nn = blockIdx.z ? n2 : n1;
    int b = blockIdx.y;
    int wave = threadIdx.x >> 6, lane = threadIdx.x & 63;
    int row = blockIdx.x * 4 + wave;
    const float4 v = *(const float4*)(d + ((size_t)b * NN + row) * DD + lane * 4);
    float s = v.x * v.x + v.y * v.y + v.z * v.z + v.w * v.w;
    #pragma unroll
    for (int off = 1; off < 64; off <<= 1) s += __shfl_xor(s, off);
    if (lane == 0) nn[b * NN + row] = s;
}

// ---------------- scores GEMM: S[n][m] = -max(n1+n2-2*dot, 0) --------
__global__ __launch_bounds__(256) void gemm_scores(const float* __restrict__ d1,
                                                   const float* __restrict__ d2,
                                                   const float* __restrict__ n1,
                                                   const float* __restrict__ n2,
                                                   float* __restrict__ out) {
    __shared__ float As[8][128];
    __shared__ float Bs[8][128];
    const int b = blockIdx.z;
    const int n0 = blockIdx.y * 128;
    const int m0 = blockIdx.x * 128;
    const int t = threadIdx.x;
    const int tx = t & 15, ty = t >> 4;
    const int lrow = t >> 1, lk = (t & 1) * 4;
    const float* A = d1 + (size_t)b * NN * DD;
    const float* Bm = d2 + (size_t)b * NN * DD;

    float acc[8][8];
    #pragma unroll
    for (int i = 0; i < 8; ++i)
        #pragma unroll
        for (int j = 0; j < 8; ++j) acc[i][j] = 0.f;

    for (int k0 = 0; k0 < DD; k0 += 8) {
        float4 av = *(const float4*)(A + (size_t)(n0 + lrow) * DD + k0 + lk);
        float4 bv = *(const float4*)(Bm + (size_t)(m0 + lrow) * DD + k0 + lk);
        __syncthreads();
        As[lk + 0][lrow] = av.x; As[lk + 1][lrow] = av.y;
        As[lk + 2][lrow] = av.z; As[lk + 3][lrow] = av.w;
        Bs[lk + 0][lrow] = bv.x; Bs[lk + 1][lrow] = bv.y;
        Bs[lk + 2][lrow] = bv.z; Bs[lk + 3][lrow] = bv.w;
        __syncthreads();
        #pragma unroll
        for (int k = 0; k < 8; ++k) {
            float a[8], bb[8];
            *(float4*)(a)      = *(const float4*)(&As[k][ty * 8]);
            *(float4*)(a + 4)  = *(const float4*)(&As[k][ty * 8 + 4]);
            *(float4*)(bb)     = *(const float4*)(&Bs[k][tx * 8]);
            *(float4*)(bb + 4) = *(const float4*)(&Bs[k][tx * 8 + 4]);
            #pragma unroll
            for (int i = 0; i < 8; ++i)
                #pragma unroll
                for (int j = 0; j < 8; ++j)
                    acc[i][j] = fmaf(a[i], bb[j], acc[i][j]);
        }
    }
    float rn[8], cn[8];
    #pragma unroll
    for (int i = 0; i < 8; ++i) rn[i] = n1[b * NN + n0 + ty * 8 + i];
    #pragma unroll
    for (int j = 0; j < 8; ++j) cn[j] = n2[b * NN + m0 + tx * 8 + j];
    #pragma unroll
    for (int i = 0; i < 8; ++i) {
        int n = n0 + ty * 8 + i;
        float* orow = out + ((size_t)b * NP + n) * NP + m0 + tx * 8;
        #pragma unroll
        for (int j = 0; j < 8; ++j)
            orow[j] = -fmaxf(rn[i] + cn[j] - 2.f * acc[i][j], 0.f);
    }
}

// ---------------- dustbin row/col fill (-1.0) ------------------------
__global__ void pad_fill(float* __restrict__ out) {
    int b = blockIdx.y;
    int idx = blockIdx.x * 256 + threadIdx.x;
    if (blockIdx.z == 0) {
        if (idx < NP) out[((size_t)b * NP + NN) * NP + idx] = -1.f;
    } else {
        if (idx < NN) out[((size_t)b * NP + idx) * NP + NN] = -1.f;
    }
}

// ---------------- u update: one block per (b, n) row -----------------
__global__ __launch_bounds__(256) void row_lse(const float* __restrict__ S,
                                               const float* __restrict__ v,
                                               float* __restrict__ u) {
    int n = blockIdx.x;
    int b = blockIdx.y;
    const float* row = S + ((size_t)b * NP + n) * NP;
    const float* vb = v + b * NP;
    float m = -INFINITY, s = 0.f;
    for (int i = threadIdx.x; i < NP; i += 256) {
        float x = row[i] + vb[i];
        float nm = fmaxf(m, x);
        s = s * __expf(m - nm) + __expf(x - nm);
        m = nm;
    }
    #pragma unroll
    for (int off = 1; off < 64; off <<= 1) {
        float om = __shfl_xor(m, off);
        float os = __shfl_xor(s, off);
        lse_comb(m, s, om, os);
    }
    __shared__ float sm[4], ss[4];
    int wave = threadIdx.x >> 6, lane = threadIdx.x & 63;
    if (lane == 0) { sm[wave] = m; ss[wave] = s; }
    __syncthreads();
    if (threadIdx.x == 0) {
        float M0 = sm[0], S0 = ss[0];
        #pragma unroll
        for (int w = 1; w < 4; ++w) lse_comb(M0, S0, sm[w], ss[w]);
        float mu = (n == NN) ? LOG2048 : 0.f;
        u[b * NP + n] = mu - (M0 + __logf(S0));
    }
}

// ---------------- v update: partial column LSE over row chunks -------
__global__ __launch_bounds__(256) void col_lse_part(const float* __restrict__ S,
                                                    const float* __restrict__ u,
                                                    float* __restrict__ pm,
                                                    float* __restrict__ ps) {
    int ct = blockIdx.x;   // 0..CT-1
    int rc = blockIdx.y;   // 0..RCH-1
    int b = blockIdx.z;
    int m = ct * 256 + threadIdx.x;
    float mm = -INFINITY, ssum = 0.f;
    if (m < NP) {
        const float* ub = u + b * NP;
        int r0 = rc * CHUNK;
        int r1 = r0 + CHUNK; if (r1 > NP) r1 = NP;
        const float* p = S + ((size_t)b * NP + r0) * NP + m;
        for (int n = r0; n < r1; ++n, p += NP) {
            float x = *p + ub[n];
            float nm = fmaxf(mm, x);
            ssum = ssum * __expf(mm - nm) + __expf(x - nm);
            mm = nm;
        }
    }
    size_t idx = (((size_t)b * CT + ct) * RCH + rc) * 256 + threadIdx.x;
    pm[idx] = mm;
    ps[idx] = ssum;
}

__global__ void col_lse_comb(const float* __restrict__ pm,
                             const float* __restrict__ ps,
                             float* __restrict__ v) {
    int ct = blockIdx.x;
    int b = blockIdx.y;
    int m = ct * 256 + threadIdx.x;
    if (m >= NP) return;
    float mm = -INFINITY, ssum = 0.f;
    for (int rc = 0; rc < RCH; ++rc) {
        size_t idx = (((size_t)b * CT + ct) * RCH + rc) * 256 + threadIdx.x;
        lse_comb(mm, ssum, pm[idx], ps[idx]);
    }
    float nu = (m == NN) ? LOG2048 : 0.f;
    v[b * NP + m] = nu - (mm + __logf(ssum));
}

// ---------------- finalize: P = exp(S + u + v) in place --------------
__global__ void finalize_k(float* __restrict__ S,
                           const float* __restrict__ u,
                           const float* __restrict__ v) {
    int b = blockIdx.z;
    int n = blockIdx.y;
    int m = blockIdx.x * 256 + threadIdx.x;
    if (m >= NP) return;
    size_t off = ((size_t)b * NP + n) * NP;
    S[off + m] = __expf(S[off + m] + u[b * NP + n] + v[b * NP + m]);
}

extern "C" void kernel_launch(void* const* d_in, const int* in_sizes, int n_in,
                              void* d_out, int out_size, void* d_ws, size_t ws_size,
                              hipStream_t stream) {
    const float* d1 = (const float*)d_in[0];
    const float* d2 = (const float*)d_in[1];
    float* out = (float*)d_out;

    float* n1 = (float*)d_ws;                 // BB*NN
    float* n2 = n1 + BB * NN;                 // BB*NN
    float* u  = n2 + BB * NN;                 // BB*NP
    float* v  = u + BB * NP;                  // BB*NP
    float* pm = v + BB * NP;                  // BB*CT*RCH*256
    float* ps = pm + (size_t)BB * CT * RCH * 256;

    hipMemsetAsync(v, 0, (size_t)BB * NP * sizeof(float), stream);

    norms_k<<<dim3(NN / 4, BB, 2), 256, 0, stream>>>(d1, d2, n1, n2);
    gemm_scores<<<dim3(16, 16, BB), 256, 0, stream>>>(d1, d2, n1, n2, out);
    pad_fill<<<dim3(CT, BB, 2), 256, 0, stream>>>(out);

    for (int it = 0; it < 20; ++it) {
        row_lse<<<dim3(NP, BB), 256, 0, stream>>>(out, v, u);
        col_lse_part<<<dim3(CT, RCH, BB), 256, 0, stream>>>(out, u, pm, ps);
        col_lse_comb<<<dim3(CT, BB), 256, 0, stream>>>(pm, ps, v);
    }
    finalize_k<<<dim3(CT, NP, BB), 256, 0, stream>>>(out, u, v);
}

// Round 2
// 833.817 us; speedup vs baseline: 2.3837x; 2.3837x over previous
//
#include <hip/hip_runtime.h>
#include <math.h>

#define BB 8
#define NN 2048
#define DD 256
#define NP 2049
#define CT 9            // ceil(2049/256)
#define E1 0.36787944117144233f   // exp(-1)

// ---------------- norms: n[b][r] = sum_d d[b][r][d]^2 ----------------
__global__ __launch_bounds__(256) void norms_k(const float* __restrict__ d1,
                                               const float* __restrict__ d2,
                                               float* __restrict__ n1,
                                               float* __restrict__ n2) {
    const float* d = blockIdx.z ? d2 : d1;
    float* nn = blockIdx.z ? n2 : n1;
    int b = blockIdx.y;
    int wave = threadIdx.x >> 6, lane = threadIdx.x & 63;
    int row = blockIdx.x * 4 + wave;
    const float4 v = *(const float4*)(d + ((size_t)b * NN + row) * DD + lane * 4);
    float s = v.x * v.x + v.y * v.y + v.z * v.z + v.w * v.w;
    #pragma unroll
    for (int off = 1; off < 64; off <<= 1) s += __shfl_xor(s, off);
    if (lane == 0) nn[b * NN + row] = s;
}

// ------------- scores: K[n][m] = exp(-max(n1+n2-2*dot, 0)) -----------
__global__ __launch_bounds__(256) void gemm_scores(const float* __restrict__ d1,
                                                   const float* __restrict__ d2,
                                                   const float* __restrict__ n1,
                                                   const float* __restrict__ n2,
                                                   float* __restrict__ out) {
    __shared__ float As[8][128];
    __shared__ float Bs[8][128];
    const int b = blockIdx.z;
    const int n0 = blockIdx.y * 128;
    const int m0 = blockIdx.x * 128;
    const int t = threadIdx.x;
    const int tx = t & 15, ty = t >> 4;
    const int lrow = t >> 1, lk = (t & 1) * 4;
    const float* A = d1 + (size_t)b * NN * DD;
    const float* Bm = d2 + (size_t)b * NN * DD;

    float acc[8][8];
    #pragma unroll
    for (int i = 0; i < 8; ++i)
        #pragma unroll
        for (int j = 0; j < 8; ++j) acc[i][j] = 0.f;

    for (int k0 = 0; k0 < DD; k0 += 8) {
        float4 av = *(const float4*)(A + (size_t)(n0 + lrow) * DD + k0 + lk);
        float4 bv = *(const float4*)(Bm + (size_t)(m0 + lrow) * DD + k0 + lk);
        __syncthreads();
        As[lk + 0][lrow] = av.x; As[lk + 1][lrow] = av.y;
        As[lk + 2][lrow] = av.z; As[lk + 3][lrow] = av.w;
        Bs[lk + 0][lrow] = bv.x; Bs[lk + 1][lrow] = bv.y;
        Bs[lk + 2][lrow] = bv.z; Bs[lk + 3][lrow] = bv.w;
        __syncthreads();
        #pragma unroll
        for (int k = 0; k < 8; ++k) {
            float a[8], bb[8];
            *(float4*)(a)      = *(const float4*)(&As[k][ty * 8]);
            *(float4*)(a + 4)  = *(const float4*)(&As[k][ty * 8 + 4]);
            *(float4*)(bb)     = *(const float4*)(&Bs[k][tx * 8]);
            *(float4*)(bb + 4) = *(const float4*)(&Bs[k][tx * 8 + 4]);
            #pragma unroll
            for (int i = 0; i < 8; ++i)
                #pragma unroll
                for (int j = 0; j < 8; ++j)
                    acc[i][j] = fmaf(a[i], bb[j], acc[i][j]);
        }
    }
    float rn[8], cn[8];
    #pragma unroll
    for (int i = 0; i < 8; ++i) rn[i] = n1[b * NN + n0 + ty * 8 + i];
    #pragma unroll
    for (int j = 0; j < 8; ++j) cn[j] = n2[b * NN + m0 + tx * 8 + j];
    #pragma unroll
    for (int i = 0; i < 8; ++i) {
        int n = n0 + ty * 8 + i;
        float* orow = out + ((size_t)b * NP + n) * NP + m0 + tx * 8;
        #pragma unroll
        for (int j = 0; j < 8; ++j)
            orow[j] = __expf(-fmaxf(rn[i] + cn[j] - 2.f * acc[i][j], 0.f));
    }
}

// ---------------- dustbin row/col fill (exp(-1)) ---------------------
__global__ void pad_fill(float* __restrict__ out) {
    int b = blockIdx.y;
    int idx = blockIdx.x * 256 + threadIdx.x;
    if (blockIdx.z == 0) {
        if (idx < NP) out[((size_t)b * NP + NN) * NP + idx] = E1;
    } else {
        if (idx < NN) out[((size_t)b * NP + idx) * NP + NN] = E1;
    }
}

// ---------------- b init: b = exp(v0) = 1 ----------------------------
__global__ void init_b(float* __restrict__ bvec) {
    int b = blockIdx.y;
    int i = blockIdx.x * 256 + threadIdx.x;
    if (i < NP) bvec[(size_t)b * NP + i] = 1.0f;
}

// ------ fused iteration: a = mu/(K b) + partial column sums K^T a ----
// RS rows per block, processed in groups of 8 (kept in registers).
template<int RS>
__global__ __launch_bounds__(512) void fused_iter(const float* __restrict__ K,
                                                  const float* __restrict__ bvec,
                                                  float* __restrict__ avec,
                                                  float* __restrict__ part) {
    constexpr int NST = NN / RS;
    const int b = blockIdx.y;
    const int st = blockIdx.x;
    const int t = threadIdx.x;              // 0..511
    const int r0 = st * RS;
    const float* Kb = K + (size_t)b * NP * NP;
    const float* bb = bvec + (size_t)b * NP;

    __shared__ float sm[8][8];
    __shared__ float a_sh[8];
    __shared__ float sbw[8];

    float bcol[4];
    #pragma unroll
    for (int k = 0; k < 4; ++k) bcol[k] = bb[t + 512 * k];
    const float btail = bb[NN];

    // stripe 0 computes the dustbin-row a: a_N = M / (e^-1 * sum(b))
    if (st == 0) {
        float sb = bcol[0] + bcol[1] + bcol[2] + bcol[3];
        #pragma unroll
        for (int off = 1; off < 64; off <<= 1) sb += __shfl_xor(sb, off);
        if ((t & 63) == 0) sbw[t >> 6] = sb;
        __syncthreads();
        if (t == 0) {
            float tot = btail;
            #pragma unroll
            for (int w = 0; w < 8; ++w) tot += sbw[w];
            avec[(size_t)b * NP + NN] = 2048.0f / (E1 * tot);
        }
        __syncthreads();
    }

    float cp[4] = {0.f, 0.f, 0.f, 0.f};

    for (int g = 0; g < RS / 8; ++g) {
        float kr[8][4];
        const float* rp = Kb + (size_t)(r0 + g * 8) * NP + t;
        #pragma unroll
        for (int r = 0; r < 8; ++r)
            #pragma unroll
            for (int k = 0; k < 4; ++k)
                kr[r][k] = rp[(size_t)r * NP + 512 * k];
        // row sums (dot with b)
        #pragma unroll
        for (int r = 0; r < 8; ++r) {
            float p = kr[r][0] * bcol[0];
            p = fmaf(kr[r][1], bcol[1], p);
            p = fmaf(kr[r][2], bcol[2], p);
            p = fmaf(kr[r][3], bcol[3], p);
            #pragma unroll
            for (int off = 1; off < 64; off <<= 1) p += __shfl_xor(p, off);
            if ((t & 63) == 0) sm[r][t >> 6] = p;
        }
        __syncthreads();
        if (t < 64) {
            int r = t >> 3, w = t & 7;
            float p = sm[r][w];
            p += __shfl_xor(p, 1); p += __shfl_xor(p, 2); p += __shfl_xor(p, 4);
            if (w == 0) {
                float a = 1.0f / (p + E1 * btail);   // mu = 1 for core rows
                a_sh[r] = a;
                avec[(size_t)b * NP + r0 + g * 8 + r] = a;
            }
        }
        __syncthreads();
        // column partials for this group of rows
        #pragma unroll
        for (int r = 0; r < 8; ++r) {
            float a = a_sh[r];
            #pragma unroll
            for (int k = 0; k < 4; ++k) cp[k] = fmaf(kr[r][k], a, cp[k]);
        }
        __syncthreads();
    }
    float* pp = part + ((size_t)b * NST + st) * NN;
    #pragma unroll
    for (int k = 0; k < 4; ++k) pp[t + 512 * k] = cp[k];
}

// ------ combine partial column sums -> b = nu / colsum ---------------
template<int NST>
__global__ __launch_bounds__(256) void combine_k(const float* __restrict__ part,
                                                 const float* __restrict__ avec,
                                                 float* __restrict__ bvec) {
    const int b = blockIdx.y;
    const int t = threadIdx.x;
    const int m = blockIdx.x * 32 + (t & 31);
    const int g = t >> 5;
    __shared__ float red[8][32];
    __shared__ float aw[4];

    float s = 0.f;
    for (int st = g; st < NST; st += 8)
        s += part[((size_t)b * NST + st) * NN + m];
    red[g][t & 31] = s;
    __syncthreads();
    if (t < 32) {
        float tot = 0.f;
        #pragma unroll
        for (int gg = 0; gg < 8; ++gg) tot += red[gg][t];
        tot += E1 * avec[(size_t)b * NP + NN];      // dustbin-row contribution
        bvec[(size_t)b * NP + m] = 1.0f / tot;      // nu = 1 for core cols
    }
    if (blockIdx.x == 0) {
        // dustbin column: b_M = N / (e^-1 * sum(a))
        float sa = 0.f;
        #pragma unroll
        for (int k = 0; k < 8; ++k) sa += avec[(size_t)b * NP + t + 256 * k];
        #pragma unroll
        for (int off = 1; off < 64; off <<= 1) sa += __shfl_xor(sa, off);
        if ((t & 63) == 0) aw[t >> 6] = sa;
        __syncthreads();
        if (t == 0) {
            float tot = aw[0] + aw[1] + aw[2] + aw[3] + avec[(size_t)b * NP + NN];
            bvec[(size_t)b * NP + NN] = 2048.0f / (E1 * tot);
        }
    }
}

// ---------------- finalize: P = a_n * K * b_m in place ---------------
__global__ __launch_bounds__(256) void finalize_k(float* __restrict__ out,
                                                  const float* __restrict__ avec,
                                                  const float* __restrict__ bvec) {
    int b = blockIdx.z;
    int n = blockIdx.y;
    int m = blockIdx.x * 256 + threadIdx.x;
    if (m >= NP) return;
    size_t off = ((size_t)b * NP + n) * NP;
    out[off + m] = out[off + m] * avec[(size_t)b * NP + n] * bvec[(size_t)b * NP + m];
}

extern "C" void kernel_launch(void* const* d_in, const int* in_sizes, int n_in,
                              void* d_out, int out_size, void* d_ws, size_t ws_size,
                              hipStream_t stream) {
    const float* d1 = (const float*)d_in[0];
    const float* d2 = (const float*)d_in[1];
    float* out = (float*)d_out;

    float* n1 = (float*)d_ws;                 // BB*NN
    float* n2 = n1 + BB * NN;                 // BB*NN
    float* av = n2 + BB * NN;                 // BB*NP
    float* bv = av + BB * NP;                 // BB*NP
    float* part = bv + BB * NP;               // BB*NST*NN

    const size_t base_fl = (size_t)2 * BB * NN + (size_t)2 * BB * NP;
    const size_t need64 = (base_fl + (size_t)BB * 64 * NN) * sizeof(float);
    const bool big = ws_size >= need64;

    norms_k<<<dim3(NN / 4, BB, 2), 256, 0, stream>>>(d1, d2, n1, n2);
    gemm_scores<<<dim3(16, 16, BB), 256, 0, stream>>>(d1, d2, n1, n2, out);
    pad_fill<<<dim3(CT, BB, 2), 256, 0, stream>>>(out);
    init_b<<<dim3(CT, BB), 256, 0, stream>>>(bv);

    if (big) {
        for (int it = 0; it < 20; ++it) {
            fused_iter<32><<<dim3(64, BB), 512, 0, stream>>>(out, bv, av, part);
            combine_k<64><<<dim3(64, BB), 256, 0, stream>>>(part, av, bv);
        }
    } else {
        for (int it = 0; it < 20; ++it) {
            fused_iter<64><<<dim3(32, BB), 512, 0, stream>>>(out, bv, av, part);
            combine_k<32><<<dim3(64, BB), 256, 0, stream>>>(part, av, bv);
        }
    }
    finalize_k<<<dim3(CT, NP, BB), 256, 0, stream>>>(out, av, bv);
}

// Round 3
// 558.242 us; speedup vs baseline: 3.5604x; 1.4936x over previous
//
#include <hip/hip_runtime.h>
#include <math.h>

#define BB 8
#define NN 2048
#define DD 256
#define NP 2049
#define CT 9            // ceil(2049/256)
#define E1 0.36787944117144233f   // exp(-1)
#define PADK 40         // LDS bf16 row stride (80 B = 5*16B, conflict-breaking)

typedef __attribute__((ext_vector_type(8))) short bf16x8;
typedef __attribute__((ext_vector_type(4))) float f32x4;

__device__ __forceinline__ unsigned short f2bf(float x) {
    unsigned int u = __builtin_bit_cast(unsigned int, x);
    unsigned int r = (u + 0x7FFFu + ((u >> 16) & 1u)) >> 16;
    return (unsigned short)r;
}
__device__ __forceinline__ float bf2f(unsigned short h) {
    unsigned int u = ((unsigned int)h) << 16;
    return __builtin_bit_cast(float, u);
}

__device__ __forceinline__ void lse_comb(float& m, float& s, float om, float os) {
    float nm = fmaxf(m, om);
    s = s * __expf(m - nm) + os * __expf(om - nm);
    m = nm;
}

// ---------------- norms: n[b][r] = sum_d d[b][r][d]^2 ----------------
__global__ __launch_bounds__(256) void norms_k(const float* __restrict__ d1,
                                               const float* __restrict__ d2,
                                               float* __restrict__ n1,
                                               float* __restrict__ n2) {
    const float* d = blockIdx.z ? d2 : d1;
    float* nn = blockIdx.z ? n2 : n1;
    int b = blockIdx.y;
    int wave = threadIdx.x >> 6, lane = threadIdx.x & 63;
    int row = blockIdx.x * 4 + wave;
    const float4 v = *(const float4*)(d + ((size_t)b * NN + row) * DD + lane * 4);
    float s = v.x * v.x + v.y * v.y + v.z * v.z + v.w * v.w;
    #pragma unroll
    for (int off = 1; off < 64; off <<= 1) s += __shfl_xor(s, off);
    if (lane == 0) nn[b * NN + row] = s;
}

// ======== MFMA path: K core (bf16) = exp(-max(n1+n2-2*dot,0)) ========
// split-bf16: dot = hi*hi + hi*lo + lo*hi  (lo*lo dropped, err ~1e-4)
__global__ __launch_bounds__(256) void gemm_mfma(const float* __restrict__ d1,
                                                 const float* __restrict__ d2,
                                                 const float* __restrict__ n1,
                                                 const float* __restrict__ n2,
                                                 unsigned short* __restrict__ Kc) {
    __shared__ unsigned short Ah[128 * PADK];
    __shared__ unsigned short Al[128 * PADK];
    __shared__ unsigned short Bh[128 * PADK];
    __shared__ unsigned short Bl[128 * PADK];

    const int b = blockIdx.z;
    const int n0 = blockIdx.y * 128, m0 = blockIdx.x * 128;
    const int t = threadIdx.x;
    const int wave = t >> 6, lane = t & 63;
    const int wr = (wave >> 1) * 64;      // wave row offset (2x2 wave grid)
    const int wc = (wave & 1) * 64;
    const float* A  = d1 + ((size_t)b * NN + n0) * DD;
    const float* Bm = d2 + ((size_t)b * NN + m0) * DD;

    const int lrow = t >> 3;              // 0..31
    const int lk   = (t & 7) * 4;         // 0..28

    f32x4 zero = {0.f, 0.f, 0.f, 0.f};
    f32x4 acc[4][4];
    #pragma unroll
    for (int i = 0; i < 4; ++i)
        #pragma unroll
        for (int j = 0; j < 4; ++j) acc[i][j] = zero;

    const int rb = lane & 15;             // fragment row/col-in-tile
    const int kg = (lane >> 4) * 8;       // k element group (bf16 elems)

    for (int k0 = 0; k0 < DD; k0 += 32) {
        __syncthreads();
        #pragma unroll
        for (int rr = 0; rr < 4; ++rr) {
            int row = lrow + rr * 32;
            float4 a4 = *(const float4*)(A  + (size_t)row * DD + k0 + lk);
            float4 b4 = *(const float4*)(Bm + (size_t)row * DD + k0 + lk);
            ushort4 h, l;
            h.x = f2bf(a4.x); l.x = f2bf(a4.x - bf2f(h.x));
            h.y = f2bf(a4.y); l.y = f2bf(a4.y - bf2f(h.y));
            h.z = f2bf(a4.z); l.z = f2bf(a4.z - bf2f(h.z));
            h.w = f2bf(a4.w); l.w = f2bf(a4.w - bf2f(h.w));
            *(ushort4*)&Ah[row * PADK + lk] = h;
            *(ushort4*)&Al[row * PADK + lk] = l;
            h.x = f2bf(b4.x); l.x = f2bf(b4.x - bf2f(h.x));
            h.y = f2bf(b4.y); l.y = f2bf(b4.y - bf2f(h.y));
            h.z = f2bf(b4.z); l.z = f2bf(b4.z - bf2f(h.z));
            h.w = f2bf(b4.w); l.w = f2bf(b4.w - bf2f(h.w));
            *(ushort4*)&Bh[row * PADK + lk] = h;
            *(ushort4*)&Bl[row * PADK + lk] = l;
        }
        __syncthreads();

        bf16x8 ah[4], al[4], bh[4], bl[4];
        #pragma unroll
        for (int f = 0; f < 4; ++f) {
            int ar = (wr + f * 16 + rb) * PADK + kg;
            int br = (wc + f * 16 + rb) * PADK + kg;
            ah[f] = *(const bf16x8*)&Ah[ar];
            al[f] = *(const bf16x8*)&Al[ar];
            bh[f] = *(const bf16x8*)&Bh[br];
            bl[f] = *(const bf16x8*)&Bl[br];
        }
        #pragma unroll
        for (int i = 0; i < 4; ++i)
            #pragma unroll
            for (int j = 0; j < 4; ++j) {
                acc[i][j] = __builtin_amdgcn_mfma_f32_16x16x32_bf16(ah[i], bh[j], acc[i][j], 0, 0, 0);
                acc[i][j] = __builtin_amdgcn_mfma_f32_16x16x32_bf16(ah[i], bl[j], acc[i][j], 0, 0, 0);
                acc[i][j] = __builtin_amdgcn_mfma_f32_16x16x32_bf16(al[i], bh[j], acc[i][j], 0, 0, 0);
            }
    }

    // epilogue: D col = lane&15, row = (lane>>4)*4 + reg
    const int rloc0 = (lane >> 4) * 4;
    #pragma unroll
    for (int i = 0; i < 4; ++i) {
        #pragma unroll
        for (int jj = 0; jj < 4; ++jj) {
            int r = wr + i * 16 + rloc0 + jj;
            float rn = n1[b * NN + n0 + r];
            unsigned short* orow = Kc + ((size_t)b * NN + n0 + r) * NN + m0;
            #pragma unroll
            for (int j = 0; j < 4; ++j) {
                int c = wc + j * 16 + rb;
                float cn = n2[b * NN + m0 + c];
                float dot = acc[i][j][jj];
                float val = __expf(-fmaxf(rn + cn - 2.f * dot, 0.f));
                orow[c] = f2bf(val);
            }
        }
    }
}

// ---------------- b init: b = 1 --------------------------------------
__global__ void init_b(float* __restrict__ bvec) {
    int b = blockIdx.y;
    int i = blockIdx.x * 256 + threadIdx.x;
    if (i < NP) bvec[(size_t)b * NP + i] = 1.0f;
}

// ---- fused iteration over bf16 K: a = mu/(K b), partial K^T a -------
__global__ __launch_bounds__(512) void fused_iter_bf(const unsigned short* __restrict__ Kc,
                                                     const float* __restrict__ bvec,
                                                     float* __restrict__ avec,
                                                     float* __restrict__ part) {
    const int b = blockIdx.y, st = blockIdx.x, t = threadIdx.x;
    const int r0 = st * 32;
    const unsigned short* Kb = Kc + (size_t)b * NN * NN;
    const float* bb = bvec + (size_t)b * NP;
    __shared__ float sm[8][8];
    __shared__ float a_sh[8];
    __shared__ float sbw[8];

    const float4 bc = *(const float4*)(bb + 4 * t);
    const float btail = bb[NN];

    if (st == 0) {  // dustbin-row a: a_N = M / (e^-1 * sum(b))
        float sb = bc.x + bc.y + bc.z + bc.w;
        #pragma unroll
        for (int off = 1; off < 64; off <<= 1) sb += __shfl_xor(sb, off);
        if ((t & 63) == 0) sbw[t >> 6] = sb;
        __syncthreads();
        if (t == 0) {
            float tot = btail;
            #pragma unroll
            for (int w = 0; w < 8; ++w) tot += sbw[w];
            avec[(size_t)b * NP + NN] = 2048.0f / (E1 * tot);
        }
        __syncthreads();
    }

    float cp0 = 0.f, cp1 = 0.f, cp2 = 0.f, cp3 = 0.f;

    for (int g = 0; g < 4; ++g) {
        const unsigned short* rp = Kb + (size_t)(r0 + g * 8) * NN + 4 * t;
        uint2 w[8];
        #pragma unroll
        for (int r = 0; r < 8; ++r) w[r] = *(const uint2*)(rp + (size_t)r * NN);
        float kr[8][4];
        #pragma unroll
        for (int r = 0; r < 8; ++r) {
            kr[r][0] = bf2f((unsigned short)(w[r].x & 0xFFFFu));
            kr[r][1] = bf2f((unsigned short)(w[r].x >> 16));
            kr[r][2] = bf2f((unsigned short)(w[r].y & 0xFFFFu));
            kr[r][3] = bf2f((unsigned short)(w[r].y >> 16));
        }
        #pragma unroll
        for (int r = 0; r < 8; ++r) {
            float p = kr[r][0] * bc.x;
            p = fmaf(kr[r][1], bc.y, p);
            p = fmaf(kr[r][2], bc.z, p);
            p = fmaf(kr[r][3], bc.w, p);
            #pragma unroll
            for (int off = 1; off < 64; off <<= 1) p += __shfl_xor(p, off);
            if ((t & 63) == 0) sm[r][t >> 6] = p;
        }
        __syncthreads();
        if (t < 64) {
            int r = t >> 3, w8 = t & 7;
            float p = sm[r][w8];
            p += __shfl_xor(p, 1); p += __shfl_xor(p, 2); p += __shfl_xor(p, 4);
            if (w8 == 0) {
                float a = 1.0f / (p + E1 * btail);
                a_sh[r] = a;
                avec[(size_t)b * NP + r0 + g * 8 + r] = a;
            }
        }
        __syncthreads();
        #pragma unroll
        for (int r = 0; r < 8; ++r) {
            float a = a_sh[r];
            cp0 = fmaf(kr[r][0], a, cp0);
            cp1 = fmaf(kr[r][1], a, cp1);
            cp2 = fmaf(kr[r][2], a, cp2);
            cp3 = fmaf(kr[r][3], a, cp3);
        }
        __syncthreads();
    }
    float4 cpv = {cp0, cp1, cp2, cp3};
    *(float4*)(part + ((size_t)b * 64 + st) * NN + 4 * t) = cpv;
}

// ------ combine partial column sums -> b = nu / colsum ---------------
template<int NST>
__global__ __launch_bounds__(256) void combine_k(const float* __restrict__ part,
                                                 const float* __restrict__ avec,
                                                 float* __restrict__ bvec) {
    const int b = blockIdx.y;
    const int t = threadIdx.x;
    const int m = blockIdx.x * 32 + (t & 31);
    const int g = t >> 5;
    __shared__ float red[8][32];
    __shared__ float aw[4];

    float s = 0.f;
    for (int st = g; st < NST; st += 8)
        s += part[((size_t)b * NST + st) * NN + m];
    red[g][t & 31] = s;
    __syncthreads();
    if (t < 32) {
        float tot = 0.f;
        #pragma unroll
        for (int gg = 0; gg < 8; ++gg) tot += red[gg][t];
        tot += E1 * avec[(size_t)b * NP + NN];
        bvec[(size_t)b * NP + m] = 1.0f / tot;
    }
    if (blockIdx.x == 0) {
        float sa = 0.f;
        #pragma unroll
        for (int k = 0; k < 8; ++k) sa += avec[(size_t)b * NP + t + 256 * k];
        #pragma unroll
        for (int off = 1; off < 64; off <<= 1) sa += __shfl_xor(sa, off);
        if ((t & 63) == 0) aw[t >> 6] = sa;
        __syncthreads();
        if (t == 0) {
            float tot = aw[0] + aw[1] + aw[2] + aw[3] + avec[(size_t)b * NP + NN];
            bvec[(size_t)b * NP + NN] = 2048.0f / (E1 * tot);
        }
    }
}

// ---- finalize (bf16 path): P = a_n * K * b_m, dustbins analytic -----
__global__ __launch_bounds__(256) void finalize_bf(const unsigned short* __restrict__ Kc,
                                                   const float* __restrict__ avec,
                                                   const float* __restrict__ bvec,
                                                   float* __restrict__ out) {
    int b = blockIdx.z;
    int n = blockIdx.y;
    int m = blockIdx.x * 256 + threadIdx.x;
    if (m > NN) return;
    float a = avec[(size_t)b * NP + n];
    float bm = bvec[(size_t)b * NP + m];
    float k;
    if (n < NN && m < NN) k = bf2f(Kc[((size_t)b * NN + n) * NN + m]);
    else k = E1;
    out[((size_t)b * NP + n) * NP + m] = a * k * bm;
}

// ===================== fp32 fallback path (round-2) ==================
__global__ __launch_bounds__(256) void gemm_scores(const float* __restrict__ d1,
                                                   const float* __restrict__ d2,
                                                   const float* __restrict__ n1,
                                                   const float* __restrict__ n2,
                                                   float* __restrict__ out) {
    __shared__ float As[8][128];
    __shared__ float Bs[8][128];
    const int b = blockIdx.z;
    const int n0 = blockIdx.y * 128;
    const int m0 = blockIdx.x * 128;
    const int t = threadIdx.x;
    const int tx = t & 15, ty = t >> 4;
    const int lrow = t >> 1, lk = (t & 1) * 4;
    const float* A = d1 + (size_t)b * NN * DD;
    const float* Bm = d2 + (size_t)b * NN * DD;

    float acc[8][8];
    #pragma unroll
    for (int i = 0; i < 8; ++i)
        #pragma unroll
        for (int j = 0; j < 8; ++j) acc[i][j] = 0.f;

    for (int k0 = 0; k0 < DD; k0 += 8) {
        float4 av = *(const float4*)(A + (size_t)(n0 + lrow) * DD + k0 + lk);
        float4 bv = *(const float4*)(Bm + (size_t)(m0 + lrow) * DD + k0 + lk);
        __syncthreads();
        As[lk + 0][lrow] = av.x; As[lk + 1][lrow] = av.y;
        As[lk + 2][lrow] = av.z; As[lk + 3][lrow] = av.w;
        Bs[lk + 0][lrow] = bv.x; Bs[lk + 1][lrow] = bv.y;
        Bs[lk + 2][lrow] = bv.z; Bs[lk + 3][lrow] = bv.w;
        __syncthreads();
        #pragma unroll
        for (int k = 0; k < 8; ++k) {
            float a[8], bb[8];
            *(float4*)(a)      = *(const float4*)(&As[k][ty * 8]);
            *(float4*)(a + 4)  = *(const float4*)(&As[k][ty * 8 + 4]);
            *(float4*)(bb)     = *(const float4*)(&Bs[k][tx * 8]);
            *(float4*)(bb + 4) = *(const float4*)(&Bs[k][tx * 8 + 4]);
            #pragma unroll
            for (int i = 0; i < 8; ++i)
                #pragma unroll
                for (int j = 0; j < 8; ++j)
                    acc[i][j] = fmaf(a[i], bb[j], acc[i][j]);
        }
    }
    float rn[8], cn[8];
    #pragma unroll
    for (int i = 0; i < 8; ++i) rn[i] = n1[b * NN + n0 + ty * 8 + i];
    #pragma unroll
    for (int j = 0; j < 8; ++j) cn[j] = n2[b * NN + m0 + tx * 8 + j];
    #pragma unroll
    for (int i = 0; i < 8; ++i) {
        int n = n0 + ty * 8 + i;
        float* orow = out + ((size_t)b * NP + n) * NP + m0 + tx * 8;
        #pragma unroll
        for (int j = 0; j < 8; ++j)
            orow[j] = __expf(-fmaxf(rn[i] + cn[j] - 2.f * acc[i][j], 0.f));
    }
}

__global__ void pad_fill(float* __restrict__ out) {
    int b = blockIdx.y;
    int idx = blockIdx.x * 256 + threadIdx.x;
    if (blockIdx.z == 0) {
        if (idx < NP) out[((size_t)b * NP + NN) * NP + idx] = E1;
    } else {
        if (idx < NN) out[((size_t)b * NP + idx) * NP + NN] = E1;
    }
}

template<int RS>
__global__ __launch_bounds__(512) void fused_iter(const float* __restrict__ K,
                                                  const float* __restrict__ bvec,
                                                  float* __restrict__ avec,
                                                  float* __restrict__ part) {
    constexpr int NST = NN / RS;
    const int b = blockIdx.y;
    const int st = blockIdx.x;
    const int t = threadIdx.x;
    const int r0 = st * RS;
    const float* Kb = K + (size_t)b * NP * NP;
    const float* bb = bvec + (size_t)b * NP;

    __shared__ float sm[8][8];
    __shared__ float a_sh[8];
    __shared__ float sbw[8];

    float bcol[4];
    #pragma unroll
    for (int k = 0; k < 4; ++k) bcol[k] = bb[t + 512 * k];
    const float btail = bb[NN];

    if (st == 0) {
        float sb = bcol[0] + bcol[1] + bcol[2] + bcol[3];
        #pragma unroll
        for (int off = 1; off < 64; off <<= 1) sb += __shfl_xor(sb, off);
        if ((t & 63) == 0) sbw[t >> 6] = sb;
        __syncthreads();
        if (t == 0) {
            float tot = btail;
            #pragma unroll
            for (int w = 0; w < 8; ++w) tot += sbw[w];
            avec[(size_t)b * NP + NN] = 2048.0f / (E1 * tot);
        }
        __syncthreads();
    }

    float cp[4] = {0.f, 0.f, 0.f, 0.f};

    for (int g = 0; g < RS / 8; ++g) {
        float kr[8][4];
        const float* rp = Kb + (size_t)(r0 + g * 8) * NP + t;
        #pragma unroll
        for (int r = 0; r < 8; ++r)
            #pragma unroll
            for (int k = 0; k < 4; ++k)
                kr[r][k] = rp[(size_t)r * NP + 512 * k];
        #pragma unroll
        for (int r = 0; r < 8; ++r) {
            float p = kr[r][0] * bcol[0];
            p = fmaf(kr[r][1], bcol[1], p);
            p = fmaf(kr[r][2], bcol[2], p);
            p = fmaf(kr[r][3], bcol[3], p);
            #pragma unroll
            for (int off = 1; off < 64; off <<= 1) p += __shfl_xor(p, off);
            if ((t & 63) == 0) sm[r][t >> 6] = p;
        }
        __syncthreads();
        if (t < 64) {
            int r = t >> 3, w = t & 7;
            float p = sm[r][w];
            p += __shfl_xor(p, 1); p += __shfl_xor(p, 2); p += __shfl_xor(p, 4);
            if (w == 0) {
                float a = 1.0f / (p + E1 * btail);
                a_sh[r] = a;
                avec[(size_t)b * NP + r0 + g * 8 + r] = a;
            }
        }
        __syncthreads();
        #pragma unroll
        for (int r = 0; r < 8; ++r) {
            float a = a_sh[r];
            #pragma unroll
            for (int k = 0; k < 4; ++k) cp[k] = fmaf(kr[r][k], a, cp[k]);
        }
        __syncthreads();
    }
    float* pp = part + ((size_t)b * NST + st) * NN;
    #pragma unroll
    for (int k = 0; k < 4; ++k) pp[t + 512 * k] = cp[k];
}

__global__ __launch_bounds__(256) void finalize_k(float* __restrict__ out,
                                                  const float* __restrict__ avec,
                                                  const float* __restrict__ bvec) {
    int b = blockIdx.z;
    int n = blockIdx.y;
    int m = blockIdx.x * 256 + threadIdx.x;
    if (m >= NP) return;
    size_t off = ((size_t)b * NP + n) * NP;
    out[off + m] = out[off + m] * avec[(size_t)b * NP + n] * bvec[(size_t)b * NP + m];
}

// =====================================================================
extern "C" void kernel_launch(void* const* d_in, const int* in_sizes, int n_in,
                              void* d_out, int out_size, void* d_ws, size_t ws_size,
                              hipStream_t stream) {
    const float* d1 = (const float*)d_in[0];
    const float* d2 = (const float*)d_in[1];
    float* out = (float*)d_out;

    const size_t KCB = (size_t)BB * NN * NN * sizeof(unsigned short);   // 67.1 MB
    const size_t fl_cnt = (size_t)2 * BB * NN + (size_t)2 * BB * NP + (size_t)BB * 64 * NN;
    const size_t need_bf = KCB + fl_cnt * sizeof(float);

    if (ws_size >= need_bf) {
        // -------- bf16 MFMA path --------
        unsigned short* Kc = (unsigned short*)d_ws;
        float* n1 = (float*)((char*)d_ws + KCB);
        float* n2 = n1 + BB * NN;
        float* av = n2 + BB * NN;
        float* bv = av + BB * NP;
        float* part = bv + BB * NP;          // BB*64*NN

        norms_k<<<dim3(NN / 4, BB, 2), 256, 0, stream>>>(d1, d2, n1, n2);
        gemm_mfma<<<dim3(16, 16, BB), 256, 0, stream>>>(d1, d2, n1, n2, Kc);
        init_b<<<dim3(CT, BB), 256, 0, stream>>>(bv);

        for (int it = 0; it < 20; ++it) {
            fused_iter_bf<<<dim3(64, BB), 512, 0, stream>>>(Kc, bv, av, part);
            combine_k<64><<<dim3(64, BB), 256, 0, stream>>>(part, av, bv);
        }
        finalize_bf<<<dim3(CT, NP, BB), 256, 0, stream>>>(Kc, av, bv, out);
    } else {
        // -------- fp32 fallback (round-2 proven path) --------
        float* n1 = (float*)d_ws;
        float* n2 = n1 + BB * NN;
        float* av = n2 + BB * NN;
        float* bv = av + BB * NP;
        float* part = bv + BB * NP;

        const size_t base_fl = (size_t)2 * BB * NN + (size_t)2 * BB * NP;
        const size_t need64 = (base_fl + (size_t)BB * 64 * NN) * sizeof(float);
        const bool big = ws_size >= need64;

        norms_k<<<dim3(NN / 4, BB, 2), 256, 0, stream>>>(d1, d2, n1, n2);
        gemm_scores<<<dim3(16, 16, BB), 256, 0, stream>>>(d1, d2, n1, n2, out);
        pad_fill<<<dim3(CT, BB, 2), 256, 0, stream>>>(out);
        init_b<<<dim3(CT, BB), 256, 0, stream>>>(bv);

        if (big) {
            for (int it = 0; it < 20; ++it) {
                fused_iter<32><<<dim3(64, BB), 512, 0, stream>>>(out, bv, av, part);
                combine_k<64><<<dim3(64, BB), 256, 0, stream>>>(part, av, bv);
            }
        } else {
            for (int it = 0; it < 20; ++it) {
                fused_iter<64><<<dim3(32, BB), 512, 0, stream>>>(out, bv, av, part);
                combine_k<32><<<dim3(64, BB), 256, 0, stream>>>(part, av, bv);
            }
        }
        finalize_k<<<dim3(CT, NP, BB), 256, 0, stream>>>(out, av, bv);
    }
}